// Round 10
// baseline (218.492 us; speedup 1.0000x reference)
//
#include <hip/hip_runtime.h>

typedef unsigned char  u8;
typedef unsigned short u16;
typedef unsigned int   u32;
typedef unsigned long long u64;
typedef __attribute__((ext_vector_type(8))) short bf16x8;
typedef __attribute__((ext_vector_type(4))) float f32x4;

#define NOBS 128
#define NN   1280
#define NH   256
#define NO   80
#define TT   5
#define RR   16          // batch rows per block
#define NTHR 512         // 8 waves/block, 2 col-tiles per wave
#define BP1  88          // layer1 bits LDS pitch (u16)
#define BP2  20          // layer2/3 bits pitch (u16)

// Inline near-correctly-rounded f32 exp via f64 degree-11 Taylor.
__device__ __forceinline__ float exp_cr(float arg) {
  double xa = (double)arg;
  double nd = __builtin_rint(xa * 1.4426950408889634074);
  double r  = fma(nd, -6.93147180369123816490e-01, xa);
  r         = fma(nd, -1.90821492927058770002e-10, r);
  double p = 2.50521083854417187751e-08;
  p = fma(p, r, 2.75573192239858906526e-07);
  p = fma(p, r, 2.75573192239858906526e-06);
  p = fma(p, r, 2.48015873015873015873e-05);
  p = fma(p, r, 1.98412698412698412698e-04);
  p = fma(p, r, 1.38888888888888888889e-03);
  p = fma(p, r, 8.33333333333333333333e-03);
  p = fma(p, r, 4.16666666666666666667e-02);
  p = fma(p, r, 1.66666666666666666667e-01);
  p = fma(p, r, 0.5);
  p = fma(p, r, 1.0);
  p = fma(p, r, 1.0);
  int n = (int)nd;
  union { u64 u; double d; } s;
  s.u = ((u64)(u32)(n + 1023)) << 52;
  return (n < -150) ? 0.f : (float)(s.d * p);
}

// In-register 3-way bf16 split of 8 f32 (R8-verified on silicon: bit-identical
// to the prep split3 — same RNE formula, same exact subtractions):
//   t = bits + 0x7FFF + ((bits>>16)&1);  hi = t>>16;  hi_f = t & 0xFFFF0000.
__device__ __forceinline__ void split8(f32x4 va, f32x4 vb,
                                       bf16x8* H, bf16x8* M, bf16x8* L) {
  union { f32x4 v; float f[4]; } A, B; A.v = va; B.v = vb;
  union { u32 u[4]; bf16x8 v; } h, m, l;
  #pragma unroll
  for (int p = 0; p < 4; ++p) {
    float w0 = (p < 2) ? A.f[2 * p]     : B.f[2 * (p - 2)];
    float w1 = (p < 2) ? A.f[2 * p + 1] : B.f[2 * (p - 2) + 1];
    u32 x0 = __float_as_uint(w0);
    u32 t0 = x0 + 0x7FFFu + ((x0 >> 16) & 1u);
    float r10 = __fsub_rn(w0, __uint_as_float(t0 & 0xFFFF0000u));   // exact
    u32 y0 = __float_as_uint(r10);
    u32 s0 = y0 + 0x7FFFu + ((y0 >> 16) & 1u);
    float r20 = __fsub_rn(r10, __uint_as_float(s0 & 0xFFFF0000u));  // exact
    u32 z0 = __float_as_uint(r20);
    u32 g0 = (z0 + 0x7FFFu + ((z0 >> 16) & 1u)) >> 16;
    u32 x1 = __float_as_uint(w1);
    u32 t1 = x1 + 0x7FFFu + ((x1 >> 16) & 1u);
    float r11 = __fsub_rn(w1, __uint_as_float(t1 & 0xFFFF0000u));
    u32 y1 = __float_as_uint(r11);
    u32 s1 = y1 + 0x7FFFu + ((y1 >> 16) & 1u);
    float r21 = __fsub_rn(r11, __uint_as_float(s1 & 0xFFFF0000u));
    u32 z1 = __float_as_uint(r21);
    u32 g1 = (z1 + 0x7FFFu + ((z1 >> 16) & 1u)) >> 16;
    h.u[p] = (t0 >> 16) | (t1 & 0xFFFF0000u);
    m.u[p] = (s0 >> 16) | (s1 & 0xFFFF0000u);
    l.u[p] = g0 | (g1 << 16);
  }
  *H = h.v; *M = m.v; *L = l.v;
}

// A-fragment: 8 spike bits x 5 t -> bf16 0/1 fragments via 16-entry LDS LUT.
// Entry n lives on banks 2n/2n+1 (all 16 disjoint); same-entry reads
// broadcast -> conflict-free. Values bit-identical to the ALU expansion.
__device__ __forceinline__ void build_afr(
    const u16* lbits, int bpitch, int kc, int ks, int m16, int sh,
    const u64* __restrict__ lut, bf16x8 afr[TT])
{
  #pragma unroll
  for (int t = 0; t < TT; ++t) {
    u32 bwv = *(const u32*)(lbits + (t * RR + m16) * bpitch + kc * 4 + ks * 2);
    u32 b = (bwv >> sh) & 0xFFu;
    union { u64 d[2]; bf16x8 v; } x;
    x.d[0] = lut[b & 15u];
    x.d[1] = lut[b >> 4];
    afr[t] = x.v;
  }
}

// Raw-f32 direct-to-register GEMM with fused in-register split (R10).
// No workspace, no LDS staging, no prep kernel. Per kcks each lane loads its
// 16 f32 (rows m16 / m16+16 of the wave's 32-col group, k-chunk q — 64B,
// LESS than the 96B of expanded 3-plane ws), splits to hi/mid/lo bf16
// in-register (split8 = R8-verified bit-identical to prep split3), and runs
// the same 30-MFMA sequence. Per acc ELEMENT the accumulation order is
// kc:(ks0:hi,mid,lo),(ks1:hi,mid,lo) — identical to all prior rounds (the
// acc[0]-burst-then-acc[1]-burst regrouping only reorders independent
// elements). H/M/L recomputed per row-group to cap VGPRs (~116 total).
// Next-kcks f32 loads are issued before the MFMA burst (~582cy) — the
// compiler inserts counted vmcnt (the R9-proven discipline).
__device__ __forceinline__ void gemm_rawreg(
    const u16* lbits, int bpitch,
    const float* __restrict__ r0p, const float* __restrict__ r1p,  // lane ptrs @ chunk q
    int nkc, const u64* __restrict__ lut,
    int m16, int sh, f32x4 acc[2][TT])
{
  const int nst2 = nkc * 2;
  f32x4 ca0 = *(const f32x4*)(r0p);
  f32x4 ca1 = *(const f32x4*)(r0p + 4);
  f32x4 cb0 = *(const f32x4*)(r1p);
  f32x4 cb1 = *(const f32x4*)(r1p + 4);

  for (int kcks = 0; kcks < nst2; ++kcks) {
    const int kc = kcks >> 1, ks = kcks & 1;
    bf16x8 afr[TT];
    build_afr(lbits, bpitch, kc, ks, m16, sh, lut, afr);
    // prefetch next kcks' 16 f32 (issued before the MFMA burst)
    f32x4 na0 = ca0, na1 = ca1, nb0 = cb0, nb1 = cb1;
    if (kcks + 1 < nst2) {
      const float* p0 = r0p + (kcks + 1) * 32;
      const float* p1 = r1p + (kcks + 1) * 32;
      na0 = *(const f32x4*)(p0);
      na1 = *(const f32x4*)(p0 + 4);
      nb0 = *(const f32x4*)(p1);
      nb1 = *(const f32x4*)(p1 + 4);
    }
    bf16x8 H, M, L;
    split8(ca0, ca1, &H, &M, &L);          // row group 0 (cols m16)
    #pragma unroll
    for (int t = 0; t < TT; ++t)
      acc[0][t] = __builtin_amdgcn_mfma_f32_16x16x32_bf16(afr[t], H, acc[0][t], 0, 0, 0);
    #pragma unroll
    for (int t = 0; t < TT; ++t)
      acc[0][t] = __builtin_amdgcn_mfma_f32_16x16x32_bf16(afr[t], M, acc[0][t], 0, 0, 0);
    #pragma unroll
    for (int t = 0; t < TT; ++t)
      acc[0][t] = __builtin_amdgcn_mfma_f32_16x16x32_bf16(afr[t], L, acc[0][t], 0, 0, 0);
    split8(cb0, cb1, &H, &M, &L);          // row group 1 (cols m16+16)
    #pragma unroll
    for (int t = 0; t < TT; ++t)
      acc[1][t] = __builtin_amdgcn_mfma_f32_16x16x32_bf16(afr[t], H, acc[1][t], 0, 0, 0);
    #pragma unroll
    for (int t = 0; t < TT; ++t)
      acc[1][t] = __builtin_amdgcn_mfma_f32_16x16x32_bf16(afr[t], M, acc[1][t], 0, 0, 0);
    #pragma unroll
    for (int t = 0; t < TT; ++t)
      acc[1][t] = __builtin_amdgcn_mfma_f32_16x16x32_bf16(afr[t], L, acc[1][t], 0, 0, 0);
    ca0 = na0; ca1 = na1; cb0 = nb0; cb1 = nb1;
  }
}

// LIF recurrence over t; emit spike bits via ballot. 2 col-tiles per wave.
__device__ __forceinline__ void recur_spikes2(
    f32x4 acc[2][TT], const float* __restrict__ bias,
    int lane, int wv, u16* sbits, int spitch)
{
  const int q = lane >> 4, m16 = lane & 15;
  #pragma unroll
  for (int i = 0; i < 2; ++i) {
    int ct = wv * 2 + i;
    int j = ct * 16 + m16;
    float bj = bias[j];
    #pragma unroll
    for (int rg = 0; rg < 4; ++rg) {
      float c = 0.f, v = 0.f, sprev = 0.f;
      #pragma unroll
      for (int t = 0; t < TT; ++t) {
        float u = acc[i][t][rg];
        c = __fadd_rn(__fadd_rn(__fmul_rn(c, 0.5f), u), bj);       // (c*0.5 + u) + b
        float vd = __fmul_rn(v, 0.75f);
        v = __fadd_rn((sprev > 0.5f) ? 0.f : vd, c);               // v*0.75*(1-s) + c
        bool sp = v > 0.5f;
        u64 mask = __ballot(sp);
        if (m16 == 0) {
          int row = q * 4 + rg;
          sbits[(t * RR + row) * spitch + ct] = (u16)(mask >> (q * 16));
        }
        sprev = sp ? 1.f : 0.f;
      }
    }
  }
}

// Single dispatch: encoder -> 3-layer SNN (raw-f32 register GEMM with fused
// split) -> decoder. No workspace, no second kernel, no cross-block
// communication. LDS 25,728B; __launch_bounds__(512,4) caps VGPR at 128 so
// 2 blocks/CU (4 waves/SIMD) is preserved.
__global__ __launch_bounds__(NTHR, 4) void snn_one(
    const float* __restrict__ obs, const float* __restrict__ enc_mean,
    const float* __restrict__ enc_std,
    const float* __restrict__ W1, const float* __restrict__ W2,
    const float* __restrict__ Wo,
    const float* __restrict__ b1, const float* __restrict__ b2, const float* __restrict__ bo,
    const float* __restrict__ dec_w, const float* __restrict__ dec_b, const float* __restrict__ log_std,
    float* __restrict__ out, int Btot)
{
  __shared__ __align__(16) u16 smem[12864];          // 25,728 B
  u16* encb = smem;                                  // [5t*16r][BP1] = 7040
  u16* s1b  = smem + 7040;                           // [5t*16r][BP2] = 1600
  u16* s2b  = smem + 8640;                           // 1600
  float* soacc = (float*)(smem + 10240);             // [16][80] f32 = 2560 u16
  u64* lutp = (u64*)(smem + 12800);                  // 16 x 8B nibble LUT

  const int tid  = threadIdx.x;
  const int lane = tid & 63;
  const int wv   = tid >> 6;          // 0..7
  const int r0   = blockIdx.x * RR;
  const int m16  = lane & 15, q = lane >> 4;
  const int sh   = q * 8;
  const int j0   = wv * 32 + m16;     // this lane's B row (group 0)

  // ---------- nibble->bf16x4 LUT (bit-identical to the ALU expansion) ------
  if (tid < 16) {
    u32 lo32 = (((tid & 3u) * 0x8001u) & 0x10001u) * 0x3F80u;
    u32 hi32 = ((((tid >> 2) & 3u) * 0x8001u) & 0x10001u) * 0x3F80u;
    lutp[tid] = (u64)lo32 | ((u64)hi32 << 32);
  }

  // ---------- fused population encoder: 16 rows x 1280 cols -> bit-planes --
  // 2560 half-items of 8 exps, exactly 5 per thread; bit-identical per-k
  // arithmetic to the original encoder.
  for (int h = tid; h < RR * 160; h += NTHR) {
    int r = h / 160, rem = h - r * 160;
    int w = rem >> 1, hi = rem & 1;
    const float* obsrow = obs + (r0 + r) * NOBS;
    u32 bits[TT] = {0, 0, 0, 0, 0};
    #pragma unroll
    for (int e = 0; e < 8; ++e) {
      int k = w * 16 + hi * 8 + e;
      int f = k / 10;
      float x  = obsrow[f];
      float m  = enc_mean[k];
      float sd = enc_std[k];
      float d  = __fsub_rn(x, m);
      float arg = __fdiv_rn(__fmul_rn(-0.5f, __fmul_rn(d, d)), __fmul_rn(sd, sd));
      float a = exp_cr(arg);
      float v = 0.f;
      #pragma unroll
      for (int t = 0; t < TT; ++t) {
        v = __fadd_rn(v, a);
        if (v > 0.999f) { bits[t] |= (1u << e); v = __fsub_rn(v, 0.999f); }
      }
    }
    u8* eb = (u8*)encb;
    #pragma unroll
    for (int t = 0; t < TT; ++t)
      eb[((t * RR + r) * BP1 + w) * 2 + hi] = (u8)bits[t];
  }
  __syncthreads();                                   // encb + LUT ready

  f32x4 acc[2][TT];
  const f32x4 zero4 = {0.f, 0.f, 0.f, 0.f};
#define ZERO_ACC() { _Pragma("unroll") for (int i = 0; i < 2; ++i) \
                     _Pragma("unroll") for (int t = 0; t < TT; ++t) acc[i][t] = zero4; }

  // ---------- layer 1: [80 x 1280] @ [1280 x 256] (3-way split fused) ------
  ZERO_ACC();
  gemm_rawreg(encb, BP1, W1 + j0 * 1280 + q * 8, W1 + (j0 + 16) * 1280 + q * 8,
              20, lutp, m16, sh, acc);
  recur_spikes2(acc, b1, lane, wv, s1b, BP2);
  __syncthreads();

  // ---------- layer 2: [80 x 256] @ [256 x 256] ----------------------------
  ZERO_ACC();
  gemm_rawreg(s1b, BP2, W2 + j0 * 256 + q * 8, W2 + (j0 + 16) * 256 + q * 8,
              4, lutp, m16, sh, acc);
  recur_spikes2(acc, b2, lane, wv, s2b, BP2);
  __syncthreads();

  // ---------- layer 3: [80 x 256] @ [256 x 80] — waves 0..2 ----------------
  // Rows >= 80 clamp to row 79 (garbage columns, discarded at writeout —
  // R8-verified pattern).
  if (wv < 3) {
    ZERO_ACC();
    const int jc0 = (j0 < NO) ? j0 : (NO - 1);
    const int jc1 = (j0 + 16 < NO) ? (j0 + 16) : (NO - 1);
    gemm_rawreg(s2b, BP2, Wo + jc0 * 256 + q * 8, Wo + jc1 * 256 + q * 8,
                4, lutp, m16, sh, acc);
    #pragma unroll
    for (int i = 0; i < 2; ++i) {
      int j = (wv * 2 + i) * 16 + m16;
      bool valid = j < NO;
      float bj = valid ? bo[j] : 0.f;
      #pragma unroll
      for (int rg = 0; rg < 4; ++rg) {
        float c = 0.f, v = 0.f, sprev = 0.f;
        int cnt = 0;
        #pragma unroll
        for (int t = 0; t < TT; ++t) {
          float u = acc[i][t][rg];
          c = __fadd_rn(__fadd_rn(__fmul_rn(c, 0.5f), u), bj);
          float vd = __fmul_rn(v, 0.75f);
          v = __fadd_rn((sprev > 0.5f) ? 0.f : vd, c);
          bool sp = v > 0.5f;
          cnt += sp ? 1 : 0;
          sprev = sp ? 1.f : 0.f;
        }
        if (valid) soacc[(q * 4 + rg) * NO + j] = __fdiv_rn((float)cnt, 5.0f);
      }
    }
  }
  __syncthreads();

  // ---------- decoder: grouped dot + ELU -----------------------------------
  if (tid < RR * 8) {
    int r = tid >> 3, a = tid & 7;
    float s = 0.f;
    const float* so = soacc + r * NO + a * 10;
    #pragma unroll
    for (int p = 0; p < 10; ++p)
      s = __fadd_rn(s, __fmul_rn(so[p], dec_w[a * 10 + p]));
    s = __fadd_rn(s, dec_b[a]);
    float mu = (s > 0.f) ? s : expm1f(s);
    out[(r0 + r) * 8 + a] = mu;
  }
  if (blockIdx.x == 0 && tid < 8) {
    out[Btot * 8 + tid] = expf(log_std[tid]);
  }
}

extern "C" void kernel_launch(void* const* d_in, const int* in_sizes, int n_in,
                              void* d_out, int out_size, void* d_ws, size_t ws_size,
                              hipStream_t stream) {
  const float* obs      = (const float*)d_in[0];
  const float* enc_mean = (const float*)d_in[1];
  const float* enc_std  = (const float*)d_in[2];
  const float* W1       = (const float*)d_in[3];
  const float* b1       = (const float*)d_in[4];
  const float* W2       = (const float*)d_in[5];
  const float* b2       = (const float*)d_in[6];
  const float* Wo       = (const float*)d_in[7];
  const float* bo       = (const float*)d_in[8];
  const float* dec_w    = (const float*)d_in[9];
  const float* dec_b    = (const float*)d_in[10];
  const float* log_std  = (const float*)d_in[11];
  float* out = (float*)d_out;
  int B = in_sizes[0] / NOBS;   // 8192

  hipLaunchKernelGGL(snn_one, dim3(B / RR), dim3(NTHR), 0, stream,
                     obs, enc_mean, enc_std, W1, W2, Wo,
                     b1, b2, bo, dec_w, dec_b, log_std, out, B);
}

// Round 11
// 175.820 us; speedup vs baseline: 1.2427x; 1.2427x over previous
//
#include <hip/hip_runtime.h>

typedef unsigned char  u8;
typedef unsigned short u16;
typedef unsigned int   u32;
typedef unsigned long long u64;
typedef __attribute__((ext_vector_type(8))) short bf16x8;
typedef __attribute__((ext_vector_type(4))) float f32x4;

#define NOBS 128
#define NN   1280
#define NH   256
#define NO   80
#define TT   5
#define RR   16          // batch rows per block
#define NTHR 512         // 8 waves/block, 2 col-tiles per wave
#define BP1  88          // layer1 bits LDS pitch (u16)
#define BP2  20          // layer2/3 bits pitch (u16)

// ws layout (u16 units), stage-contiguous: [kc][ks][sel][rows][32], rows
// XOR-swizzled within (sub-fragment s of row j stored at s ^ ((j>>1)&3)).
// W1s [20][2][3][256][32] @0 ; W2s [4][2][3][256][32] @983040 ;
// Wos [4][2][3][128][32] @1179648 (pad128)
#define W1TOT   983040
#define W2S_OFF 983040
#define WOS_OFF 1179648
#define WS_TOTAL 1277952

#define PREP_BLOCKS 208           // 53248 threads, 24 ws items each

__device__ __forceinline__ float bf2f(u16 u) {
  union { u32 i; float f; } x; x.i = ((u32)u) << 16; return x.f;
}
__device__ __forceinline__ u16 f2bf(float f) {
  union { float f; u32 i; } x; x.f = f;
  u32 i = x.i + 0x7FFFu + ((x.i >> 16) & 1u);   // RNE
  return (u16)(i >> 16);
}

// Inline near-correctly-rounded f32 exp via f64 degree-11 Taylor.
__device__ __forceinline__ float exp_cr(float arg) {
  double xa = (double)arg;
  double nd = __builtin_rint(xa * 1.4426950408889634074);
  double r  = fma(nd, -6.93147180369123816490e-01, xa);
  r         = fma(nd, -1.90821492927058770002e-10, r);
  double p = 2.50521083854417187751e-08;
  p = fma(p, r, 2.75573192239858906526e-07);
  p = fma(p, r, 2.75573192239858906526e-06);
  p = fma(p, r, 2.48015873015873015873e-05);
  p = fma(p, r, 1.98412698412698412698e-04);
  p = fma(p, r, 1.38888888888888888889e-03);
  p = fma(p, r, 8.33333333333333333333e-03);
  p = fma(p, r, 4.16666666666666666667e-02);
  p = fma(p, r, 1.66666666666666666667e-01);
  p = fma(p, r, 0.5);
  p = fma(p, r, 1.0);
  p = fma(p, r, 1.0);
  int n = (int)nd;
  union { u64 u; double d; } s;
  s.u = ((u64)(u32)(n + 1023)) << 52;
  return (n < -150) ? 0.f : (float)(s.d * p);
}

// Weight-split prep, vectorized (R5, hand-verified vs scalar mapping): each
// thread owns 8 contiguous source cols of one row and emits all 3 sel
// planes — 2 float4 loads, 8 hi/mid/lo splits, 3 coalesced 16B stores.
// Same split arithmetic and same swizzled storage positions as the original
// scalar prep -> bit-identical ws. Runs ONCE per iteration in its own
// dispatch: R10 proved in-block splitting is 512x redundant VALU poison.
__global__ __launch_bounds__(256) void prep_w(
    const float* __restrict__ W1, const float* __restrict__ W2,
    const float* __restrict__ Wo, u16* __restrict__ ws)
{
  const int T = blockIdx.x * 256 + threadIdx.x;     // < 53248 exactly
  const float* src;
  int dstb, selstep;
  bool pad = false;
  if (T < 40960) {                                  // W1 [256][1280]
    int kcks = T >> 10, r = T & 1023;
    int kc = kcks >> 1, ks = kcks & 1, j = r >> 2, kgrp = r & 3;
    int kk0 = (kgrp ^ ((j >> 1) & 3)) << 3;
    src = W1 + j * 1280 + kc * 64 + ks * 32 + kk0;
    dstb = kc * 49152 + ks * 24576 + j * 32 + kgrp * 8;
    selstep = 8192;
  } else if (T < 49152) {                           // W2 [256][256]
    int T2 = T - 40960;
    int kcks = T2 >> 10, r = T2 & 1023;
    int kc = kcks >> 1, ks = kcks & 1, j = r >> 2, kgrp = r & 3;
    int kk0 = (kgrp ^ ((j >> 1) & 3)) << 3;
    src = W2 + j * 256 + kc * 64 + ks * 32 + kk0;
    dstb = W2S_OFF + kc * 49152 + ks * 24576 + j * 32 + kgrp * 8;
    selstep = 8192;
  } else {                                          // Wo [80][256] pad to 128
    int T3 = T - 49152;
    int kcks = T3 >> 9, r = T3 & 511;
    int kc = kcks >> 1, ks = kcks & 1, j = r >> 2, kgrp = r & 3;
    int kk0 = (kgrp ^ ((j >> 1) & 3)) << 3;
    src = Wo + j * 256 + kc * 64 + ks * 32 + kk0;
    dstb = WOS_OFF + kc * 24576 + ks * 12288 + j * 32 + kgrp * 8;
    selstep = 4096;
    pad = (j >= NO);
  }
  float w[8];
  if (!pad) {
    float4 w0 = *(const float4*)src;          // 32B-aligned
    float4 w1 = *(const float4*)(src + 4);
    w[0] = w0.x; w[1] = w0.y; w[2] = w0.z; w[3] = w0.w;
    w[4] = w1.x; w[5] = w1.y; w[6] = w1.z; w[7] = w1.w;
  } else {
    #pragma unroll
    for (int e = 0; e < 8; ++e) w[e] = 0.f;
  }
  union { u16 u[8]; uint4 q; } hi, mid, lo;
  #pragma unroll
  for (int e = 0; e < 8; ++e) {
    u16 h = f2bf(w[e]);
    float r1 = __fsub_rn(w[e], bf2f(h));      // exact
    u16 m = f2bf(r1);
    float r2 = __fsub_rn(r1, bf2f(m));        // exact
    hi.u[e] = h; mid.u[e] = m; lo.u[e] = f2bf(r2);
  }
  *(uint4*)(ws + dstb)               = hi.q;
  *(uint4*)(ws + dstb + selstep)     = mid.q;
  *(uint4*)(ws + dstb + 2 * selstep) = lo.q;
}

// A-fragment: 8 spike bits x 5 t -> bf16 0/1 fragments via 16-entry LDS LUT.
// Entry n lives on banks 2n/2n+1 (all 16 disjoint); same-entry reads
// broadcast -> conflict-free. Values bit-identical to the ALU expansion.
__device__ __forceinline__ void build_afr(
    const u16* lbits, int bpitch, int kc, int ks, int m16, int sh,
    const u64* __restrict__ lut, bf16x8 afr[TT])
{
  #pragma unroll
  for (int t = 0; t < TT; ++t) {
    u32 bwv = *(const u32*)(lbits + (t * RR + m16) * bpitch + kc * 4 + ks * 2);
    u32 b = (bwv >> sh) & 0xFFu;
    union { u64 d[2]; bf16x8 v; } x;
    x.d[0] = lut[b & 15u];
    x.d[1] = lut[b >> 4];
    afr[t] = x.v;
  }
}

// Load all 6 B-fragments of one kcks (hi/mid/lo x 2 row-groups, 96B/lane).
__device__ __forceinline__ void ld6(const u16* __restrict__ pb, int selblk,
                                    bf16x8 f[6]) {
  f[0] = *(const bf16x8*)(pb);                 // sel0, rows m16
  f[1] = *(const bf16x8*)(pb + 512);           // sel0, rows m16+16
  f[2] = *(const bf16x8*)(pb + selblk);        // sel1
  f[3] = *(const bf16x8*)(pb + selblk + 512);
  f[4] = *(const bf16x8*)(pb + 2 * selblk);    // sel2
  f[5] = *(const bf16x8*)(pb + 2 * selblk + 512);
}

// One kcks' 30-MFMA burst, setprio-wrapped (waves are barrier-free and
// drift -> the attn-like regime where T5 paid). Per-acc-element order:
// sel0,sel1,sel2 with acc[0](rows m16) before acc[1](rows m16+16) per sel
// — identical to R9/R6 (bit-identical results).
__device__ __forceinline__ void burst30(const bf16x8 f[6], const bf16x8 afr[TT],
                                        f32x4 acc[2][TT]) {
  __builtin_amdgcn_s_setprio(1);
  #pragma unroll
  for (int t = 0; t < TT; ++t)
    acc[0][t] = __builtin_amdgcn_mfma_f32_16x16x32_bf16(afr[t], f[0], acc[0][t], 0, 0, 0);
  #pragma unroll
  for (int t = 0; t < TT; ++t)
    acc[1][t] = __builtin_amdgcn_mfma_f32_16x16x32_bf16(afr[t], f[1], acc[1][t], 0, 0, 0);
  #pragma unroll
  for (int t = 0; t < TT; ++t)
    acc[0][t] = __builtin_amdgcn_mfma_f32_16x16x32_bf16(afr[t], f[2], acc[0][t], 0, 0, 0);
  #pragma unroll
  for (int t = 0; t < TT; ++t)
    acc[1][t] = __builtin_amdgcn_mfma_f32_16x16x32_bf16(afr[t], f[3], acc[1][t], 0, 0, 0);
  #pragma unroll
  for (int t = 0; t < TT; ++t)
    acc[0][t] = __builtin_amdgcn_mfma_f32_16x16x32_bf16(afr[t], f[4], acc[0][t], 0, 0, 0);
  #pragma unroll
  for (int t = 0; t < TT; ++t)
    acc[1][t] = __builtin_amdgcn_mfma_f32_16x16x32_bf16(afr[t], f[5], acc[1][t], 0, 0, 0);
  __builtin_amdgcn_s_setprio(0);
}

// Direct-to-register GEMM, whole-kcks ping-pong prefetch (R11). R9's
// rotating 2-slot prefetch forced a wait + register moves before EVERY
// 10-MFMA stage; here all 6 fragments of kcks+1 are loaded in one shot
// before kcks' 30-MFMA burst (unroll-by-2, P/Q buffers, no moves), giving
// one counted vmcnt per kcks and a full-kcks (~800cy) slack >> load
// latency. Fragment values and per-element accumulation order
// kc:(ks0:hi,mid,lo),(ks1:hi,mid,lo) — bit-identical to all prior rounds.
__device__ __forceinline__ void gemm_pp(
    const u16* lbits, int bpitch,
    const u16* __restrict__ wsbase, int nkc, int selblk,
    const u64* __restrict__ lut, int wv, int lane, f32x4 acc[2][TT])
{
  const int m16 = lane & 15, q = lane >> 4;
  const int swz = (q ^ ((m16 >> 1) & 3)) * 8;
  const int sh = q * 8;
  const int kstep = 3 * selblk;            // one kcks' span in ws
  const u16* pb = wsbase + wv * 1024 + m16 * 32 + swz;

  bf16x8 P[6], Q[6], afr[TT];
  ld6(pb, selblk, P);
  // nkc*2 is even for all layers (40, 8, 8) -> clean unroll-by-2.
  for (int kcks = 0; kcks < nkc * 2; kcks += 2) {
    const int kc = kcks >> 1;
    build_afr(lbits, bpitch, kc, 0, m16, sh, lut, afr);
    ld6(pb + kstep, selblk, Q);                    // kcks+1, flies under burst
    burst30(P, afr, acc);
    build_afr(lbits, bpitch, kc, 1, m16, sh, lut, afr);
    if (kcks + 2 < nkc * 2)
      ld6(pb + 2 * kstep, selblk, P);              // kcks+2, flies under burst
    burst30(Q, afr, acc);
    pb += 2 * kstep;
  }
}

// LIF recurrence over t; emit spike bits via ballot. 2 col-tiles per wave.
__device__ __forceinline__ void recur_spikes2(
    f32x4 acc[2][TT], const float* __restrict__ bias,
    int lane, int wv, u16* sbits, int spitch)
{
  const int q = lane >> 4, m16 = lane & 15;
  #pragma unroll
  for (int i = 0; i < 2; ++i) {
    int ct = wv * 2 + i;
    int j = ct * 16 + m16;
    float bj = bias[j];
    #pragma unroll
    for (int rg = 0; rg < 4; ++rg) {
      float c = 0.f, v = 0.f, sprev = 0.f;
      #pragma unroll
      for (int t = 0; t < TT; ++t) {
        float u = acc[i][t][rg];
        c = __fadd_rn(__fadd_rn(__fmul_rn(c, 0.5f), u), bj);       // (c*0.5 + u) + b
        float vd = __fmul_rn(v, 0.75f);
        v = __fadd_rn((sprev > 0.5f) ? 0.f : vd, c);               // v*0.75*(1-s) + c
        bool sp = v > 0.5f;
        u64 mask = __ballot(sp);
        if (m16 == 0) {
          int row = q * 4 + rg;
          sbits[(t * RR + row) * spitch + ct] = (u16)(mask >> (q * 16));
        }
        sprev = sp ? 1.f : 0.f;
      }
    }
  }
}

__global__ __launch_bounds__(NTHR, 4) void snn_main(
    const float* __restrict__ obs, const float* __restrict__ enc_mean,
    const float* __restrict__ enc_std,
    const float* __restrict__ b1, const float* __restrict__ b2, const float* __restrict__ bo,
    const float* __restrict__ dec_w, const float* __restrict__ dec_b, const float* __restrict__ log_std,
    const u16* __restrict__ wsW, float* __restrict__ out, int Btot)
{
  __shared__ __align__(16) u16 smem[12864];          // 25,728 B (no staging bufs)
  u16* encb = smem;                                  // [5t*16r][BP1] = 7040
  u16* s1b  = smem + 7040;                           // [5t*16r][BP2] = 1600
  u16* s2b  = smem + 8640;                           // 1600
  float* soacc = (float*)(smem + 10240);             // [16][80] f32 = 2560 u16
  u64* lutp = (u64*)(smem + 12800);                  // 16 x 8B nibble LUT

  const int tid  = threadIdx.x;
  const int lane = tid & 63;
  const int wv   = tid >> 6;          // 0..7
  const int r0   = blockIdx.x * RR;

  // ---------- nibble->bf16x4 LUT (bit-identical to the ALU expansion) ------
  if (tid < 16) {
    u32 lo32 = (((tid & 3u) * 0x8001u) & 0x10001u) * 0x3F80u;
    u32 hi32 = ((((tid >> 2) & 3u) * 0x8001u) & 0x10001u) * 0x3F80u;
    lutp[tid] = (u64)lo32 | ((u64)hi32 << 32);
  }

  // ---------- fused population encoder: 16 rows x 1280 cols -> bit-planes --
  // 2560 half-items of 8 exps, exactly 5 per thread; bit-identical per-k
  // arithmetic to the original encoder.
  for (int h = tid; h < RR * 160; h += NTHR) {
    int r = h / 160, rem = h - r * 160;
    int w = rem >> 1, hi = rem & 1;
    const float* obsrow = obs + (r0 + r) * NOBS;
    u32 bits[TT] = {0, 0, 0, 0, 0};
    #pragma unroll
    for (int e = 0; e < 8; ++e) {
      int k = w * 16 + hi * 8 + e;
      int f = k / 10;
      float x  = obsrow[f];
      float m  = enc_mean[k];
      float sd = enc_std[k];
      float d  = __fsub_rn(x, m);
      float arg = __fdiv_rn(__fmul_rn(-0.5f, __fmul_rn(d, d)), __fmul_rn(sd, sd));
      float a = exp_cr(arg);
      float v = 0.f;
      #pragma unroll
      for (int t = 0; t < TT; ++t) {
        v = __fadd_rn(v, a);
        if (v > 0.999f) { bits[t] |= (1u << e); v = __fsub_rn(v, 0.999f); }
      }
    }
    u8* eb = (u8*)encb;
    #pragma unroll
    for (int t = 0; t < TT; ++t)
      eb[((t * RR + r) * BP1 + w) * 2 + hi] = (u8)bits[t];
  }
  __syncthreads();                                   // encb + LUT ready

  f32x4 acc[2][TT];
  const f32x4 zero4 = {0.f, 0.f, 0.f, 0.f};
#define ZERO_ACC() { _Pragma("unroll") for (int i = 0; i < 2; ++i) \
                     _Pragma("unroll") for (int t = 0; t < TT; ++t) acc[i][t] = zero4; }

  // ---------- layer 1: [80 x 1280] @ [1280 x 256] (3-way split fused) ------
  ZERO_ACC();
  gemm_pp(encb, BP1, wsW, 20, 8192, lutp, wv, lane, acc);
  recur_spikes2(acc, b1, lane, wv, s1b, BP2);
  __syncthreads();

  // ---------- layer 2: [80 x 256] @ [256 x 256] ----------------------------
  ZERO_ACC();
  gemm_pp(s1b, BP2, wsW + W2S_OFF, 4, 8192, lutp, wv, lane, acc);
  recur_spikes2(acc, b2, lane, wv, s2b, BP2);
  __syncthreads();

  // ---------- layer 3: [80 x 256] @ [256 x 80(pad)] — waves 0..2 -----------
  if (wv < 3) {
    ZERO_ACC();
    gemm_pp(s2b, BP2, wsW + WOS_OFF, 4, 4096, lutp, wv, lane, acc);
    const int q = lane >> 4, m16 = lane & 15;
    #pragma unroll
    for (int i = 0; i < 2; ++i) {
      int j = (wv * 2 + i) * 16 + m16;
      bool valid = j < NO;
      float bj = valid ? bo[j] : 0.f;
      #pragma unroll
      for (int rg = 0; rg < 4; ++rg) {
        float c = 0.f, v = 0.f, sprev = 0.f;
        int cnt = 0;
        #pragma unroll
        for (int t = 0; t < TT; ++t) {
          float u = acc[i][t][rg];
          c = __fadd_rn(__fadd_rn(__fmul_rn(c, 0.5f), u), bj);
          float vd = __fmul_rn(v, 0.75f);
          v = __fadd_rn((sprev > 0.5f) ? 0.f : vd, c);
          bool sp = v > 0.5f;
          cnt += sp ? 1 : 0;
          sprev = sp ? 1.f : 0.f;
        }
        if (valid) soacc[(q * 4 + rg) * NO + j] = __fdiv_rn((float)cnt, 5.0f);
      }
    }
  }
  __syncthreads();

  // ---------- decoder: grouped dot + ELU -----------------------------------
  if (tid < RR * 8) {
    int r = tid >> 3, a = tid & 7;
    float s = 0.f;
    const float* so = soacc + r * NO + a * 10;
    #pragma unroll
    for (int p = 0; p < 10; ++p)
      s = __fadd_rn(s, __fmul_rn(so[p], dec_w[a * 10 + p]));
    s = __fadd_rn(s, dec_b[a]);
    float mu = (s > 0.f) ? s : expm1f(s);
    out[(r0 + r) * 8 + a] = mu;
  }
  if (blockIdx.x == 0 && tid < 8) {
    out[Btot * 8 + tid] = expf(log_std[tid]);
  }
}

extern "C" void kernel_launch(void* const* d_in, const int* in_sizes, int n_in,
                              void* d_out, int out_size, void* d_ws, size_t ws_size,
                              hipStream_t stream) {
  const float* obs      = (const float*)d_in[0];
  const float* enc_mean = (const float*)d_in[1];
  const float* enc_std  = (const float*)d_in[2];
  const float* W1       = (const float*)d_in[3];
  const float* b1       = (const float*)d_in[4];
  const float* W2       = (const float*)d_in[5];
  const float* b2       = (const float*)d_in[6];
  const float* Wo       = (const float*)d_in[7];
  const float* bo       = (const float*)d_in[8];
  const float* dec_w    = (const float*)d_in[9];
  const float* dec_b    = (const float*)d_in[10];
  const float* log_std  = (const float*)d_in[11];
  u16*   ws  = (u16*)d_ws;
  float* out = (float*)d_out;
  int B = in_sizes[0] / NOBS;   // 8192

  hipLaunchKernelGGL(prep_w, dim3(PREP_BLOCKS), dim3(256), 0, stream,
                     W1, W2, Wo, ws);
  hipLaunchKernelGGL(snn_main, dim3(B / RR), dim3(NTHR), 0, stream,
                     obs, enc_mean, enc_std, b1, b2, bo, dec_w, dec_b, log_std,
                     ws, out, B);
}

// Round 12
// 174.637 us; speedup vs baseline: 1.2511x; 1.0068x over previous
//
#include <hip/hip_runtime.h>

typedef unsigned char  u8;
typedef unsigned short u16;
typedef unsigned int   u32;
typedef unsigned long long u64;
typedef __attribute__((ext_vector_type(8))) short bf16x8;
typedef __attribute__((ext_vector_type(4))) float f32x4;

#define NOBS 128
#define NN   1280
#define NH   256
#define NO   80
#define TT   5
#define RR   16          // batch rows per block
#define NTHR 512         // 8 waves/block, 2 col-tiles per wave
#define BP1  88          // layer1 bits LDS pitch (u16)
#define BP2  20          // layer2/3 bits pitch (u16)

// ws layout (u16 units), stage-contiguous: [kc][ks][sel][rows][32], rows
// XOR-swizzled within (sub-fragment s of row j stored at s ^ ((j>>1)&3)).
// W1s [20][2][3][256][32] @0 ; W2s [4][2][3][256][32] @983040 ;
// Wos [4][2][3][128][32] @1179648 (pad128)
#define W1TOT   983040
#define W2S_OFF 983040
#define WOS_OFF 1179648
#define WS_TOTAL 1277952

#define PREP_BLOCKS 208           // 53248 threads, 24 ws items each

__device__ __forceinline__ float bf2f(u16 u) {
  union { u32 i; float f; } x; x.i = ((u32)u) << 16; return x.f;
}
__device__ __forceinline__ u16 f2bf(float f) {
  union { float f; u32 i; } x; x.f = f;
  u32 i = x.i + 0x7FFFu + ((x.i >> 16) & 1u);   // RNE
  return (u16)(i >> 16);
}

// Inline near-correctly-rounded f32 exp via f64 degree-11 Taylor.
__device__ __forceinline__ float exp_cr(float arg) {
  double xa = (double)arg;
  double nd = __builtin_rint(xa * 1.4426950408889634074);
  double r  = fma(nd, -6.93147180369123816490e-01, xa);
  r         = fma(nd, -1.90821492927058770002e-10, r);
  double p = 2.50521083854417187751e-08;
  p = fma(p, r, 2.75573192239858906526e-07);
  p = fma(p, r, 2.75573192239858906526e-06);
  p = fma(p, r, 2.48015873015873015873e-05);
  p = fma(p, r, 1.98412698412698412698e-04);
  p = fma(p, r, 1.38888888888888888889e-03);
  p = fma(p, r, 8.33333333333333333333e-03);
  p = fma(p, r, 4.16666666666666666667e-02);
  p = fma(p, r, 1.66666666666666666667e-01);
  p = fma(p, r, 0.5);
  p = fma(p, r, 1.0);
  p = fma(p, r, 1.0);
  int n = (int)nd;
  union { u64 u; double d; } s;
  s.u = ((u64)(u32)(n + 1023)) << 52;
  return (n < -150) ? 0.f : (float)(s.d * p);
}

// Weight-split prep, vectorized (R5, hand-verified vs scalar mapping).
// Bit-identical ws; runs once per iteration in its own dispatch (R10
// proved in-block splitting is 512x redundant VALU poison).
__global__ __launch_bounds__(256) void prep_w(
    const float* __restrict__ W1, const float* __restrict__ W2,
    const float* __restrict__ Wo, u16* __restrict__ ws)
{
  const int T = blockIdx.x * 256 + threadIdx.x;     // < 53248 exactly
  const float* src;
  int dstb, selstep;
  bool pad = false;
  if (T < 40960) {                                  // W1 [256][1280]
    int kcks = T >> 10, r = T & 1023;
    int kc = kcks >> 1, ks = kcks & 1, j = r >> 2, kgrp = r & 3;
    int kk0 = (kgrp ^ ((j >> 1) & 3)) << 3;
    src = W1 + j * 1280 + kc * 64 + ks * 32 + kk0;
    dstb = kc * 49152 + ks * 24576 + j * 32 + kgrp * 8;
    selstep = 8192;
  } else if (T < 49152) {                           // W2 [256][256]
    int T2 = T - 40960;
    int kcks = T2 >> 10, r = T2 & 1023;
    int kc = kcks >> 1, ks = kcks & 1, j = r >> 2, kgrp = r & 3;
    int kk0 = (kgrp ^ ((j >> 1) & 3)) << 3;
    src = W2 + j * 256 + kc * 64 + ks * 32 + kk0;
    dstb = W2S_OFF + kc * 49152 + ks * 24576 + j * 32 + kgrp * 8;
    selstep = 8192;
  } else {                                          // Wo [80][256] pad to 128
    int T3 = T - 49152;
    int kcks = T3 >> 9, r = T3 & 511;
    int kc = kcks >> 1, ks = kcks & 1, j = r >> 2, kgrp = r & 3;
    int kk0 = (kgrp ^ ((j >> 1) & 3)) << 3;
    src = Wo + j * 256 + kc * 64 + ks * 32 + kk0;
    dstb = WOS_OFF + kc * 24576 + ks * 12288 + j * 32 + kgrp * 8;
    selstep = 4096;
    pad = (j >= NO);
  }
  float w[8];
  if (!pad) {
    float4 w0 = *(const float4*)src;          // 32B-aligned
    float4 w1 = *(const float4*)(src + 4);
    w[0] = w0.x; w[1] = w0.y; w[2] = w0.z; w[3] = w0.w;
    w[4] = w1.x; w[5] = w1.y; w[6] = w1.z; w[7] = w1.w;
  } else {
    #pragma unroll
    for (int e = 0; e < 8; ++e) w[e] = 0.f;
  }
  union { u16 u[8]; uint4 q; } hi, mid, lo;
  #pragma unroll
  for (int e = 0; e < 8; ++e) {
    u16 h = f2bf(w[e]);
    float r1 = __fsub_rn(w[e], bf2f(h));      // exact
    u16 m = f2bf(r1);
    float r2 = __fsub_rn(r1, bf2f(m));        // exact
    hi.u[e] = h; mid.u[e] = m; lo.u[e] = f2bf(r2);
  }
  *(uint4*)(ws + dstb)               = hi.q;
  *(uint4*)(ws + dstb + selstep)     = mid.q;
  *(uint4*)(ws + dstb + 2 * selstep) = lo.q;
}

// A-fragment: 8 spike bits x 5 t -> bf16 0/1 fragments via 16-entry LDS LUT.
// Entry n lives on banks 2n/2n+1 (all 16 disjoint); same-entry reads
// broadcast -> conflict-free. Values bit-identical to the ALU expansion.
__device__ __forceinline__ void build_afr(
    const u16* lbits, int bpitch, int kc, int ks, int m16, int sh,
    const u64* __restrict__ lut, bf16x8 afr[TT])
{
  #pragma unroll
  for (int t = 0; t < TT; ++t) {
    u32 bwv = *(const u32*)(lbits + (t * RR + m16) * bpitch + kc * 4 + ks * 2);
    u32 b = (bwv >> sh) & 0xFFu;
    union { u64 d[2]; bf16x8 v; } x;
    x.d[0] = lut[b & 15u];
    x.d[1] = lut[b >> 4];
    afr[t] = x.v;
  }
}

// R12: R11's whole-kcks ping-pong prefetch, SCALARIZED. R11 put the P/Q
// fragment sets in arrays passed by pointer; the compiler demoted them to
// scratch (WRITE_SIZE 0.26->18MB, VGPR "64" + 36MB/dispatch spill traffic).
// Named scalars + macros make every access compile-time static (the
// R9-proven pattern). Schedule unchanged: all 6 fragments of kcks+1 load in
// one shot before kcks' 30-MFMA burst -> one counted vmcnt per kcks with a
// full-kcks (~800cy) slack. Fragment values and per-element accumulation
// order kc:(ks0:hi,mid,lo),(ks1:hi,mid,lo) — bit-identical to all rounds.

#define LD6(pfx, base) do {                                   \
    pfx##0 = *(const bf16x8*)(base);                          \
    pfx##1 = *(const bf16x8*)((base) + 512);                  \
    pfx##2 = *(const bf16x8*)((base) + selblk);               \
    pfx##3 = *(const bf16x8*)((base) + selblk + 512);         \
    pfx##4 = *(const bf16x8*)((base) + 2 * selblk);           \
    pfx##5 = *(const bf16x8*)((base) + 2 * selblk + 512);     \
  } while (0)

// Per-acc-element order: sel0,sel1,sel2; acc[0](rows m16) bursts before
// acc[1](rows m16+16) per sel — independent elements, same per-element
// order as R6/R9. setprio(1) wraps the burst (barrier-free waves drift ->
// the regime where priority arbitration can pay).
#define BURST30(F0, F1, F2, F3, F4, F5) do {                  \
    __builtin_amdgcn_s_setprio(1);                            \
    _Pragma("unroll")                                         \
    for (int t = 0; t < TT; ++t)                              \
      acc[0][t] = __builtin_amdgcn_mfma_f32_16x16x32_bf16(afr[t], F0, acc[0][t], 0, 0, 0); \
    _Pragma("unroll")                                         \
    for (int t = 0; t < TT; ++t)                              \
      acc[1][t] = __builtin_amdgcn_mfma_f32_16x16x32_bf16(afr[t], F1, acc[1][t], 0, 0, 0); \
    _Pragma("unroll")                                         \
    for (int t = 0; t < TT; ++t)                              \
      acc[0][t] = __builtin_amdgcn_mfma_f32_16x16x32_bf16(afr[t], F2, acc[0][t], 0, 0, 0); \
    _Pragma("unroll")                                         \
    for (int t = 0; t < TT; ++t)                              \
      acc[1][t] = __builtin_amdgcn_mfma_f32_16x16x32_bf16(afr[t], F3, acc[1][t], 0, 0, 0); \
    _Pragma("unroll")                                         \
    for (int t = 0; t < TT; ++t)                              \
      acc[0][t] = __builtin_amdgcn_mfma_f32_16x16x32_bf16(afr[t], F4, acc[0][t], 0, 0, 0); \
    _Pragma("unroll")                                         \
    for (int t = 0; t < TT; ++t)                              \
      acc[1][t] = __builtin_amdgcn_mfma_f32_16x16x32_bf16(afr[t], F5, acc[1][t], 0, 0, 0); \
    __builtin_amdgcn_s_setprio(0);                            \
  } while (0)

__device__ __forceinline__ void gemm_pp(
    const u16* lbits, int bpitch,
    const u16* __restrict__ wsbase, int nkc, int selblk,
    const u64* __restrict__ lut, int wv, int lane, f32x4 acc[2][TT])
{
  const int m16 = lane & 15, q = lane >> 4;
  const int swz = (q ^ ((m16 >> 1) & 3)) * 8;
  const int sh = q * 8;
  const int kstep = 3 * selblk;            // one kcks' span in ws
  const u16* pb = wsbase + wv * 1024 + m16 * 32 + swz;

  bf16x8 P0, P1, P2, P3, P4, P5;
  bf16x8 Q0, Q1, Q2, Q3, Q4, Q5;
  bf16x8 afr[TT];
  LD6(P, pb);
  // nkc*2 is even for all layers (40, 8, 8) -> clean unroll-by-2.
  for (int kcks = 0; kcks < nkc * 2; kcks += 2) {
    const int kc = kcks >> 1;
    build_afr(lbits, bpitch, kc, 0, m16, sh, lut, afr);
    LD6(Q, pb + kstep);                            // kcks+1, flies under burst
    BURST30(P0, P1, P2, P3, P4, P5);
    build_afr(lbits, bpitch, kc, 1, m16, sh, lut, afr);
    if (kcks + 2 < nkc * 2)
      LD6(P, pb + 2 * kstep);                      // kcks+2, flies under burst
    BURST30(Q0, Q1, Q2, Q3, Q4, Q5);
    pb += 2 * kstep;
  }
}

// LIF recurrence over t; emit spike bits via ballot. 2 col-tiles per wave.
__device__ __forceinline__ void recur_spikes2(
    f32x4 acc[2][TT], const float* __restrict__ bias,
    int lane, int wv, u16* sbits, int spitch)
{
  const int q = lane >> 4, m16 = lane & 15;
  #pragma unroll
  for (int i = 0; i < 2; ++i) {
    int ct = wv * 2 + i;
    int j = ct * 16 + m16;
    float bj = bias[j];
    #pragma unroll
    for (int rg = 0; rg < 4; ++rg) {
      float c = 0.f, v = 0.f, sprev = 0.f;
      #pragma unroll
      for (int t = 0; t < TT; ++t) {
        float u = acc[i][t][rg];
        c = __fadd_rn(__fadd_rn(__fmul_rn(c, 0.5f), u), bj);       // (c*0.5 + u) + b
        float vd = __fmul_rn(v, 0.75f);
        v = __fadd_rn((sprev > 0.5f) ? 0.f : vd, c);               // v*0.75*(1-s) + c
        bool sp = v > 0.5f;
        u64 mask = __ballot(sp);
        if (m16 == 0) {
          int row = q * 4 + rg;
          sbits[(t * RR + row) * spitch + ct] = (u16)(mask >> (q * 16));
        }
        sprev = sp ? 1.f : 0.f;
      }
    }
  }
}

__global__ __launch_bounds__(NTHR, 4) void snn_main(
    const float* __restrict__ obs, const float* __restrict__ enc_mean,
    const float* __restrict__ enc_std,
    const float* __restrict__ b1, const float* __restrict__ b2, const float* __restrict__ bo,
    const float* __restrict__ dec_w, const float* __restrict__ dec_b, const float* __restrict__ log_std,
    const u16* __restrict__ wsW, float* __restrict__ out, int Btot)
{
  __shared__ __align__(16) u16 smem[12864];          // 25,728 B (no staging bufs)
  u16* encb = smem;                                  // [5t*16r][BP1] = 7040
  u16* s1b  = smem + 7040;                           // [5t*16r][BP2] = 1600
  u16* s2b  = smem + 8640;                           // 1600
  float* soacc = (float*)(smem + 10240);             // [16][80] f32 = 2560 u16
  u64* lutp = (u64*)(smem + 12800);                  // 16 x 8B nibble LUT

  const int tid  = threadIdx.x;
  const int lane = tid & 63;
  const int wv   = tid >> 6;          // 0..7
  const int r0   = blockIdx.x * RR;

  // ---------- nibble->bf16x4 LUT (bit-identical to the ALU expansion) ------
  if (tid < 16) {
    u32 lo32 = (((tid & 3u) * 0x8001u) & 0x10001u) * 0x3F80u;
    u32 hi32 = ((((tid >> 2) & 3u) * 0x8001u) & 0x10001u) * 0x3F80u;
    lutp[tid] = (u64)lo32 | ((u64)hi32 << 32);
  }

  // ---------- fused population encoder: 16 rows x 1280 cols -> bit-planes --
  // 2560 half-items of 8 exps, exactly 5 per thread; bit-identical per-k
  // arithmetic to the original encoder.
  for (int h = tid; h < RR * 160; h += NTHR) {
    int r = h / 160, rem = h - r * 160;
    int w = rem >> 1, hi = rem & 1;
    const float* obsrow = obs + (r0 + r) * NOBS;
    u32 bits[TT] = {0, 0, 0, 0, 0};
    #pragma unroll
    for (int e = 0; e < 8; ++e) {
      int k = w * 16 + hi * 8 + e;
      int f = k / 10;
      float x  = obsrow[f];
      float m  = enc_mean[k];
      float sd = enc_std[k];
      float d  = __fsub_rn(x, m);
      float arg = __fdiv_rn(__fmul_rn(-0.5f, __fmul_rn(d, d)), __fmul_rn(sd, sd));
      float a = exp_cr(arg);
      float v = 0.f;
      #pragma unroll
      for (int t = 0; t < TT; ++t) {
        v = __fadd_rn(v, a);
        if (v > 0.999f) { bits[t] |= (1u << e); v = __fsub_rn(v, 0.999f); }
      }
    }
    u8* eb = (u8*)encb;
    #pragma unroll
    for (int t = 0; t < TT; ++t)
      eb[((t * RR + r) * BP1 + w) * 2 + hi] = (u8)bits[t];
  }
  __syncthreads();                                   // encb + LUT ready

  f32x4 acc[2][TT];
  const f32x4 zero4 = {0.f, 0.f, 0.f, 0.f};
#define ZERO_ACC() { _Pragma("unroll") for (int i = 0; i < 2; ++i) \
                     _Pragma("unroll") for (int t = 0; t < TT; ++t) acc[i][t] = zero4; }

  // ---------- layer 1: [80 x 1280] @ [1280 x 256] (3-way split fused) ------
  ZERO_ACC();
  gemm_pp(encb, BP1, wsW, 20, 8192, lutp, wv, lane, acc);
  recur_spikes2(acc, b1, lane, wv, s1b, BP2);
  __syncthreads();

  // ---------- layer 2: [80 x 256] @ [256 x 256] ----------------------------
  ZERO_ACC();
  gemm_pp(s1b, BP2, wsW + W2S_OFF, 4, 8192, lutp, wv, lane, acc);
  recur_spikes2(acc, b2, lane, wv, s2b, BP2);
  __syncthreads();

  // ---------- layer 3: [80 x 256] @ [256 x 80(pad)] — waves 0..2 -----------
  if (wv < 3) {
    ZERO_ACC();
    gemm_pp(s2b, BP2, wsW + WOS_OFF, 4, 4096, lutp, wv, lane, acc);
    const int q = lane >> 4, m16 = lane & 15;
    #pragma unroll
    for (int i = 0; i < 2; ++i) {
      int j = (wv * 2 + i) * 16 + m16;
      bool valid = j < NO;
      float bj = valid ? bo[j] : 0.f;
      #pragma unroll
      for (int rg = 0; rg < 4; ++rg) {
        float c = 0.f, v = 0.f, sprev = 0.f;
        int cnt = 0;
        #pragma unroll
        for (int t = 0; t < TT; ++t) {
          float u = acc[i][t][rg];
          c = __fadd_rn(__fadd_rn(__fmul_rn(c, 0.5f), u), bj);
          float vd = __fmul_rn(v, 0.75f);
          v = __fadd_rn((sprev > 0.5f) ? 0.f : vd, c);
          bool sp = v > 0.5f;
          cnt += sp ? 1 : 0;
          sprev = sp ? 1.f : 0.f;
        }
        if (valid) soacc[(q * 4 + rg) * NO + j] = __fdiv_rn((float)cnt, 5.0f);
      }
    }
  }
  __syncthreads();

  // ---------- decoder: grouped dot + ELU -----------------------------------
  if (tid < RR * 8) {
    int r = tid >> 3, a = tid & 7;
    float s = 0.f;
    const float* so = soacc + r * NO + a * 10;
    #pragma unroll
    for (int p = 0; p < 10; ++p)
      s = __fadd_rn(s, __fmul_rn(so[p], dec_w[a * 10 + p]));
    s = __fadd_rn(s, dec_b[a]);
    float mu = (s > 0.f) ? s : expm1f(s);
    out[(r0 + r) * 8 + a] = mu;
  }
  if (blockIdx.x == 0 && tid < 8) {
    out[Btot * 8 + tid] = expf(log_std[tid]);
  }
}

extern "C" void kernel_launch(void* const* d_in, const int* in_sizes, int n_in,
                              void* d_out, int out_size, void* d_ws, size_t ws_size,
                              hipStream_t stream) {
  const float* obs      = (const float*)d_in[0];
  const float* enc_mean = (const float*)d_in[1];
  const float* enc_std  = (const float*)d_in[2];
  const float* W1       = (const float*)d_in[3];
  const float* b1       = (const float*)d_in[4];
  const float* W2       = (const float*)d_in[5];
  const float* b2       = (const float*)d_in[6];
  const float* Wo       = (const float*)d_in[7];
  const float* bo       = (const float*)d_in[8];
  const float* dec_w    = (const float*)d_in[9];
  const float* dec_b    = (const float*)d_in[10];
  const float* log_std  = (const float*)d_in[11];
  u16*   ws  = (u16*)d_ws;
  float* out = (float*)d_out;
  int B = in_sizes[0] / NOBS;   // 8192

  hipLaunchKernelGGL(prep_w, dim3(PREP_BLOCKS), dim3(256), 0, stream,
                     W1, W2, Wo, ws);
  hipLaunchKernelGGL(snn_main, dim3(B / RR), dim3(NTHR), 0, stream,
                     obs, enc_mean, enc_std, b1, b2, bo, dec_w, dec_b, log_std,
                     ws, out, B);
}

// Round 13
// 157.946 us; speedup vs baseline: 1.3833x; 1.1057x over previous
//
#include <hip/hip_runtime.h>

typedef unsigned char  u8;
typedef unsigned short u16;
typedef unsigned int   u32;
typedef unsigned long long u64;
typedef __attribute__((ext_vector_type(8))) short bf16x8;
typedef __attribute__((ext_vector_type(4))) float f32x4;

#define NOBS 128
#define NN   1280
#define NH   256
#define NO   80
#define TT   5
#define RR   16          // batch rows per block
#define NTHR 512         // 8 waves/block, 2 col-tiles per wave
#define BP1  88          // layer1 bits LDS pitch (u16)
#define BP2  20          // layer2/3 bits pitch (u16)

// ws layout (u16 units), stage-contiguous: [kc][ks][sel][rows][32], rows
// XOR-swizzled within (sub-fragment s of row j stored at s ^ ((j>>1)&3)).
// W1s [20][2][3][256][32] @0 ; W2s [4][2][3][256][32] @983040 ;
// Wos [4][2][3][128][32] @1179648 (pad128)
#define W1TOT   983040
#define W2S_OFF 983040
#define WOS_OFF 1179648
#define WS_TOTAL 1277952

#define PREP_BLOCKS 208           // 53248 threads, 24 ws items each

__device__ __forceinline__ float bf2f(u16 u) {
  union { u32 i; float f; } x; x.i = ((u32)u) << 16; return x.f;
}
__device__ __forceinline__ u16 f2bf(float f) {
  union { float f; u32 i; } x; x.f = f;
  u32 i = x.i + 0x7FFFu + ((x.i >> 16) & 1u);   // RNE
  return (u16)(i >> 16);
}

// Inline near-correctly-rounded f32 exp via f64 degree-11 Taylor.
__device__ __forceinline__ float exp_cr(float arg) {
  double xa = (double)arg;
  double nd = __builtin_rint(xa * 1.4426950408889634074);
  double r  = fma(nd, -6.93147180369123816490e-01, xa);
  r         = fma(nd, -1.90821492927058770002e-10, r);
  double p = 2.50521083854417187751e-08;
  p = fma(p, r, 2.75573192239858906526e-07);
  p = fma(p, r, 2.75573192239858906526e-06);
  p = fma(p, r, 2.48015873015873015873e-05);
  p = fma(p, r, 1.98412698412698412698e-04);
  p = fma(p, r, 1.38888888888888888889e-03);
  p = fma(p, r, 8.33333333333333333333e-03);
  p = fma(p, r, 4.16666666666666666667e-02);
  p = fma(p, r, 1.66666666666666666667e-01);
  p = fma(p, r, 0.5);
  p = fma(p, r, 1.0);
  p = fma(p, r, 1.0);
  int n = (int)nd;
  union { u64 u; double d; } s;
  s.u = ((u64)(u32)(n + 1023)) << 52;
  return (n < -150) ? 0.f : (float)(s.d * p);
}

// Weight-split prep, vectorized (R5, hand-verified vs scalar mapping).
// Bit-identical ws; runs once per iteration in its own dispatch (R10
// proved in-block splitting is 512x redundant VALU poison).
__global__ __launch_bounds__(256) void prep_w(
    const float* __restrict__ W1, const float* __restrict__ W2,
    const float* __restrict__ Wo, u16* __restrict__ ws)
{
  const int T = blockIdx.x * 256 + threadIdx.x;     // < 53248 exactly
  const float* src;
  int dstb, selstep;
  bool pad = false;
  if (T < 40960) {                                  // W1 [256][1280]
    int kcks = T >> 10, r = T & 1023;
    int kc = kcks >> 1, ks = kcks & 1, j = r >> 2, kgrp = r & 3;
    int kk0 = (kgrp ^ ((j >> 1) & 3)) << 3;
    src = W1 + j * 1280 + kc * 64 + ks * 32 + kk0;
    dstb = kc * 49152 + ks * 24576 + j * 32 + kgrp * 8;
    selstep = 8192;
  } else if (T < 49152) {                           // W2 [256][256]
    int T2 = T - 40960;
    int kcks = T2 >> 10, r = T2 & 1023;
    int kc = kcks >> 1, ks = kcks & 1, j = r >> 2, kgrp = r & 3;
    int kk0 = (kgrp ^ ((j >> 1) & 3)) << 3;
    src = W2 + j * 256 + kc * 64 + ks * 32 + kk0;
    dstb = W2S_OFF + kc * 49152 + ks * 24576 + j * 32 + kgrp * 8;
    selstep = 8192;
  } else {                                          // Wo [80][256] pad to 128
    int T3 = T - 49152;
    int kcks = T3 >> 9, r = T3 & 511;
    int kc = kcks >> 1, ks = kcks & 1, j = r >> 2, kgrp = r & 3;
    int kk0 = (kgrp ^ ((j >> 1) & 3)) << 3;
    src = Wo + j * 256 + kc * 64 + ks * 32 + kk0;
    dstb = WOS_OFF + kc * 24576 + ks * 12288 + j * 32 + kgrp * 8;
    selstep = 4096;
    pad = (j >= NO);
  }
  float w[8];
  if (!pad) {
    float4 w0 = *(const float4*)src;          // 32B-aligned
    float4 w1 = *(const float4*)(src + 4);
    w[0] = w0.x; w[1] = w0.y; w[2] = w0.z; w[3] = w0.w;
    w[4] = w1.x; w[5] = w1.y; w[6] = w1.z; w[7] = w1.w;
  } else {
    #pragma unroll
    for (int e = 0; e < 8; ++e) w[e] = 0.f;
  }
  union { u16 u[8]; uint4 q; } hi, mid, lo;
  #pragma unroll
  for (int e = 0; e < 8; ++e) {
    u16 h = f2bf(w[e]);
    float r1 = __fsub_rn(w[e], bf2f(h));      // exact
    u16 m = f2bf(r1);
    float r2 = __fsub_rn(r1, bf2f(m));        // exact
    hi.u[e] = h; mid.u[e] = m; lo.u[e] = f2bf(r2);
  }
  *(uint4*)(ws + dstb)               = hi.q;
  *(uint4*)(ws + dstb + selstep)     = mid.q;
  *(uint4*)(ws + dstb + 2 * selstep) = lo.q;
}

// R13: whole-kcks ping-pong prefetch with per-t A-fragment build and an
// explicit occupancy contract. R11/R12 spilled because the compiler's
// heuristic targets 64 VGPR (8 waves/SIMD capacity) — pointless here: the
// grid is 512 blocks = exactly 2 blocks/CU, so anything <=128 VGPR gives
// full residency. amdgpu_waves_per_eu(4,4) states that contract, removing
// the motive to spill. Pressure is also genuinely lowered: the A-fragment
// is rebuilt per t inside the burst (4 VGPRs live) instead of afr[5] (20).
// Per-acc-element MFMA order unchanged — acc[0][t] sees sel0,sel1,sel2 per
// kcks (F0/F2/F4), acc[1][t] F1/F3/F5, kcks ascending — bit-identical.
// One counted vmcnt per kcks (6 fragment loads fly under the 30-MFMA burst).

#define LD6(pfx, base) do {                                   \
    pfx##0 = *(const bf16x8*)(base);                          \
    pfx##1 = *(const bf16x8*)((base) + 512);                  \
    pfx##2 = *(const bf16x8*)((base) + selblk);               \
    pfx##3 = *(const bf16x8*)((base) + selblk + 512);         \
    pfx##4 = *(const bf16x8*)((base) + 2 * selblk);           \
    pfx##5 = *(const bf16x8*)((base) + 2 * selblk + 512);     \
  } while (0)

// 30 MFMAs of one kcks, t-outer; afr built per t from the LDS LUT (entry n
// on banks 2n/2n+1, all disjoint; same-entry reads broadcast ->
// conflict-free; values bit-identical to the ALU expansion). setprio wraps
// the burst (barrier-free waves drift -> priority arbitration can pay).
#define BURST_T(F0, F1, F2, F3, F4, F5, kcv, ksv) do {        \
    __builtin_amdgcn_s_setprio(1);                            \
    _Pragma("unroll")                                         \
    for (int t = 0; t < TT; ++t) {                            \
      u32 bwv = *(const u32*)(lbits + (t * RR + m16) * bpitch \
                              + (kcv) * 4 + (ksv) * 2);       \
      u32 b = (bwv >> sh) & 0xFFu;                            \
      union { u64 d[2]; bf16x8 v; } xx;                       \
      xx.d[0] = lut[b & 15u];                                 \
      xx.d[1] = lut[b >> 4];                                  \
      bf16x8 a = xx.v;                                        \
      acc[0][t] = __builtin_amdgcn_mfma_f32_16x16x32_bf16(a, F0, acc[0][t], 0, 0, 0); \
      acc[1][t] = __builtin_amdgcn_mfma_f32_16x16x32_bf16(a, F1, acc[1][t], 0, 0, 0); \
      acc[0][t] = __builtin_amdgcn_mfma_f32_16x16x32_bf16(a, F2, acc[0][t], 0, 0, 0); \
      acc[1][t] = __builtin_amdgcn_mfma_f32_16x16x32_bf16(a, F3, acc[1][t], 0, 0, 0); \
      acc[0][t] = __builtin_amdgcn_mfma_f32_16x16x32_bf16(a, F4, acc[0][t], 0, 0, 0); \
      acc[1][t] = __builtin_amdgcn_mfma_f32_16x16x32_bf16(a, F5, acc[1][t], 0, 0, 0); \
    }                                                         \
    __builtin_amdgcn_s_setprio(0);                            \
  } while (0)

__device__ __forceinline__ void gemm_pp(
    const u16* lbits, int bpitch,
    const u16* __restrict__ wsbase, int nkc, int selblk,
    const u64* __restrict__ lut, int wv, int lane, f32x4 acc[2][TT])
{
  const int m16 = lane & 15, q = lane >> 4;
  const int swz = (q ^ ((m16 >> 1) & 3)) * 8;
  const int sh = q * 8;
  const int kstep = 3 * selblk;            // one kcks' span in ws
  const u16* pb = wsbase + wv * 1024 + m16 * 32 + swz;

  bf16x8 P0, P1, P2, P3, P4, P5;
  bf16x8 Q0, Q1, Q2, Q3, Q4, Q5;
  LD6(P, pb);
  // nkc*2 is even for all layers (40, 8, 8) -> clean unroll-by-2.
  for (int kcks = 0; kcks < nkc * 2; kcks += 2) {
    const int kc = kcks >> 1;
    LD6(Q, pb + kstep);                            // kcks+1, flies under burst
    BURST_T(P0, P1, P2, P3, P4, P5, kc, 0);
    if (kcks + 2 < nkc * 2)
      LD6(P, pb + 2 * kstep);                      // kcks+2, flies under burst
    BURST_T(Q0, Q1, Q2, Q3, Q4, Q5, kc, 1);
    pb += 2 * kstep;
  }
}

// LIF recurrence over t; emit spike bits via ballot. 2 col-tiles per wave.
__device__ __forceinline__ void recur_spikes2(
    f32x4 acc[2][TT], const float* __restrict__ bias,
    int lane, int wv, u16* sbits, int spitch)
{
  const int q = lane >> 4, m16 = lane & 15;
  #pragma unroll
  for (int i = 0; i < 2; ++i) {
    int ct = wv * 2 + i;
    int j = ct * 16 + m16;
    float bj = bias[j];
    #pragma unroll
    for (int rg = 0; rg < 4; ++rg) {
      float c = 0.f, v = 0.f, sprev = 0.f;
      #pragma unroll
      for (int t = 0; t < TT; ++t) {
        float u = acc[i][t][rg];
        c = __fadd_rn(__fadd_rn(__fmul_rn(c, 0.5f), u), bj);       // (c*0.5 + u) + b
        float vd = __fmul_rn(v, 0.75f);
        v = __fadd_rn((sprev > 0.5f) ? 0.f : vd, c);               // v*0.75*(1-s) + c
        bool sp = v > 0.5f;
        u64 mask = __ballot(sp);
        if (m16 == 0) {
          int row = q * 4 + rg;
          sbits[(t * RR + row) * spitch + ct] = (u16)(mask >> (q * 16));
        }
        sprev = sp ? 1.f : 0.f;
      }
    }
  }
}

__global__ __launch_bounds__(NTHR)
__attribute__((amdgpu_waves_per_eu(4, 4)))
void snn_main(
    const float* __restrict__ obs, const float* __restrict__ enc_mean,
    const float* __restrict__ enc_std,
    const float* __restrict__ b1, const float* __restrict__ b2, const float* __restrict__ bo,
    const float* __restrict__ dec_w, const float* __restrict__ dec_b, const float* __restrict__ log_std,
    const u16* __restrict__ wsW, float* __restrict__ out, int Btot)
{
  __shared__ __align__(16) u16 smem[12864];          // 25,728 B (no staging bufs)
  u16* encb = smem;                                  // [5t*16r][BP1] = 7040
  u16* s1b  = smem + 7040;                           // [5t*16r][BP2] = 1600
  u16* s2b  = smem + 8640;                           // 1600
  float* soacc = (float*)(smem + 10240);             // [16][80] f32 = 2560 u16
  u64* lutp = (u64*)(smem + 12800);                  // 16 x 8B nibble LUT

  const int tid  = threadIdx.x;
  const int lane = tid & 63;
  const int wv   = tid >> 6;          // 0..7
  const int r0   = blockIdx.x * RR;

  // ---------- nibble->bf16x4 LUT (bit-identical to the ALU expansion) ------
  if (tid < 16) {
    u32 lo32 = (((tid & 3u) * 0x8001u) & 0x10001u) * 0x3F80u;
    u32 hi32 = ((((tid >> 2) & 3u) * 0x8001u) & 0x10001u) * 0x3F80u;
    lutp[tid] = (u64)lo32 | ((u64)hi32 << 32);
  }

  // ---------- fused population encoder: 16 rows x 1280 cols -> bit-planes --
  // 2560 half-items of 8 exps, exactly 5 per thread; bit-identical per-k
  // arithmetic to the original encoder.
  for (int h = tid; h < RR * 160; h += NTHR) {
    int r = h / 160, rem = h - r * 160;
    int w = rem >> 1, hi = rem & 1;
    const float* obsrow = obs + (r0 + r) * NOBS;
    u32 bits[TT] = {0, 0, 0, 0, 0};
    #pragma unroll
    for (int e = 0; e < 8; ++e) {
      int k = w * 16 + hi * 8 + e;
      int f = k / 10;
      float x  = obsrow[f];
      float m  = enc_mean[k];
      float sd = enc_std[k];
      float d  = __fsub_rn(x, m);
      float arg = __fdiv_rn(__fmul_rn(-0.5f, __fmul_rn(d, d)), __fmul_rn(sd, sd));
      float a = exp_cr(arg);
      float v = 0.f;
      #pragma unroll
      for (int t = 0; t < TT; ++t) {
        v = __fadd_rn(v, a);
        if (v > 0.999f) { bits[t] |= (1u << e); v = __fsub_rn(v, 0.999f); }
      }
    }
    u8* eb = (u8*)encb;
    #pragma unroll
    for (int t = 0; t < TT; ++t)
      eb[((t * RR + r) * BP1 + w) * 2 + hi] = (u8)bits[t];
  }
  __syncthreads();                                   // encb + LUT ready

  f32x4 acc[2][TT];
  const f32x4 zero4 = {0.f, 0.f, 0.f, 0.f};
#define ZERO_ACC() { _Pragma("unroll") for (int i = 0; i < 2; ++i) \
                     _Pragma("unroll") for (int t = 0; t < TT; ++t) acc[i][t] = zero4; }

  // ---------- layer 1: [80 x 1280] @ [1280 x 256] (3-way split fused) ------
  ZERO_ACC();
  gemm_pp(encb, BP1, wsW, 20, 8192, lutp, wv, lane, acc);
  recur_spikes2(acc, b1, lane, wv, s1b, BP2);
  __syncthreads();

  // ---------- layer 2: [80 x 256] @ [256 x 256] ----------------------------
  ZERO_ACC();
  gemm_pp(s1b, BP2, wsW + W2S_OFF, 4, 8192, lutp, wv, lane, acc);
  recur_spikes2(acc, b2, lane, wv, s2b, BP2);
  __syncthreads();

  // ---------- layer 3: [80 x 256] @ [256 x 80(pad)] — waves 0..2 -----------
  if (wv < 3) {
    ZERO_ACC();
    gemm_pp(s2b, BP2, wsW + WOS_OFF, 4, 4096, lutp, wv, lane, acc);
    const int q = lane >> 4, m16 = lane & 15;
    #pragma unroll
    for (int i = 0; i < 2; ++i) {
      int j = (wv * 2 + i) * 16 + m16;
      bool valid = j < NO;
      float bj = valid ? bo[j] : 0.f;
      #pragma unroll
      for (int rg = 0; rg < 4; ++rg) {
        float c = 0.f, v = 0.f, sprev = 0.f;
        int cnt = 0;
        #pragma unroll
        for (int t = 0; t < TT; ++t) {
          float u = acc[i][t][rg];
          c = __fadd_rn(__fadd_rn(__fmul_rn(c, 0.5f), u), bj);
          float vd = __fmul_rn(v, 0.75f);
          v = __fadd_rn((sprev > 0.5f) ? 0.f : vd, c);
          bool sp = v > 0.5f;
          cnt += sp ? 1 : 0;
          sprev = sp ? 1.f : 0.f;
        }
        if (valid) soacc[(q * 4 + rg) * NO + j] = __fdiv_rn((float)cnt, 5.0f);
      }
    }
  }
  __syncthreads();

  // ---------- decoder: grouped dot + ELU -----------------------------------
  if (tid < RR * 8) {
    int r = tid >> 3, a = tid & 7;
    float s = 0.f;
    const float* so = soacc + r * NO + a * 10;
    #pragma unroll
    for (int p = 0; p < 10; ++p)
      s = __fadd_rn(s, __fmul_rn(so[p], dec_w[a * 10 + p]));
    s = __fadd_rn(s, dec_b[a]);
    float mu = (s > 0.f) ? s : expm1f(s);
    out[(r0 + r) * 8 + a] = mu;
  }
  if (blockIdx.x == 0 && tid < 8) {
    out[Btot * 8 + tid] = expf(log_std[tid]);
  }
}

extern "C" void kernel_launch(void* const* d_in, const int* in_sizes, int n_in,
                              void* d_out, int out_size, void* d_ws, size_t ws_size,
                              hipStream_t stream) {
  const float* obs      = (const float*)d_in[0];
  const float* enc_mean = (const float*)d_in[1];
  const float* enc_std  = (const float*)d_in[2];
  const float* W1       = (const float*)d_in[3];
  const float* b1       = (const float*)d_in[4];
  const float* W2       = (const float*)d_in[5];
  const float* b2       = (const float*)d_in[6];
  const float* Wo       = (const float*)d_in[7];
  const float* bo       = (const float*)d_in[8];
  const float* dec_w    = (const float*)d_in[9];
  const float* dec_b    = (const float*)d_in[10];
  const float* log_std  = (const float*)d_in[11];
  u16*   ws  = (u16*)d_ws;
  float* out = (float*)d_out;
  int B = in_sizes[0] / NOBS;   // 8192

  hipLaunchKernelGGL(prep_w, dim3(PREP_BLOCKS), dim3(256), 0, stream,
                     W1, W2, Wo, ws);
  hipLaunchKernelGGL(snn_main, dim3(B / RR), dim3(NTHR), 0, stream,
                     obs, enc_mean, enc_std, b1, b2, bo, dec_w, dec_b, log_std,
                     ws, out, B);
}